// Round 6
// baseline (285.656 us; speedup 1.0000x reference)
//
#include <hip/hip_runtime.h>
#include <hip/hip_bf16.h>

#define NSEG 50000

typedef __attribute__((ext_vector_type(4))) float f32x4;
typedef __attribute__((ext_vector_type(8))) short s16x8;

static __device__ __forceinline__ unsigned short f2bf(float f) {
  unsigned int u = __float_as_uint(f);
  u += 0x7fffu + ((u >> 16) & 1u);   // round-to-nearest-even
  return (unsigned short)(u >> 16);
}

static __device__ __forceinline__ s16x8 pack_bf16x8(const float* p) {
  float4 p0 = *(const float4*)(p);
  float4 p1 = *(const float4*)(p + 4);
  s16x8 v;
  v[0] = (short)f2bf(p0.x); v[1] = (short)f2bf(p0.y);
  v[2] = (short)f2bf(p0.z); v[3] = (short)f2bf(p0.w);
  v[4] = (short)f2bf(p1.x); v[5] = (short)f2bf(p1.y);
  v[6] = (short)f2bf(p1.z); v[7] = (short)f2bf(p1.w);
  return v;
}

// ---------------------------------------------------------------------------
// prep: Wb = bf16(W) [256x128];  wb_cat[16][128] bf16 (rows 0-7: a_src-folded
// heads, rows 8-15: a_tgt-folded);  denom = 0.
// ---------------------------------------------------------------------------
__global__ __launch_bounds__(256) void prep_kernel(
    const float* __restrict__ W, const float* __restrict__ a_src,
    const float* __restrict__ a_tgt, unsigned short* __restrict__ Wb,
    unsigned short* __restrict__ wb_cat, float* __restrict__ denom) {
  int t = blockIdx.x * 256 + threadIdx.x;
  if (t < 32768) Wb[t] = f2bf(W[t]);
  if (t < 2048) {
    int row = t >> 7, k = t & 127;
    int h = row & 7;
    const float* a = (row < 8) ? a_src : a_tgt;
    float acc = 0.f;
    for (int f = 0; f < 32; ++f) acc += W[(h * 32 + f) * 128 + k] * a[h * 32 + f];
    wb_cat[t] = f2bf(acc);
  }
  if (t < NSEG * 8) denom[t] = 0.f;
}

// ---------------------------------------------------------------------------
// score: MFMA, A = wb_cat (16 rows x 128 K), B = msg rows (K x 16 edges).
// C layout: row = kgrp*4+r (head), col = lane&15 (edge).
// ---------------------------------------------------------------------------
__global__ __launch_bounds__(256) void score_kernel(
    const float* __restrict__ msg, const int* __restrict__ index,
    const unsigned short* __restrict__ wb_cat, float* __restrict__ ex,
    float* __restrict__ denom, int n) {
  int tid = threadIdx.x;
  int w = tid >> 6, l = tid & 63;
  int lcol = l & 15;   // A row / B col (edge) within tile
  int kgrp = l >> 4;   // k-chunk of 8
  int e0 = blockIdx.x * 64 + w * 16;
  int grow = e0 + lcol;
  int ga = grow < n ? grow : n - 1;
  const float* rs = msg + (size_t)ga * 128;                // msg_src row
  const float* rt = msg + ((size_t)ga + (size_t)n) * 128;  // msg_tgt row

  s16x8 afrag[4];
#pragma unroll
  for (int kk = 0; kk < 4; ++kk)
    afrag[kk] = *(const s16x8*)(wb_cat + lcol * 128 + kk * 32 + kgrp * 8);

  f32x4 ds = {0.f, 0.f, 0.f, 0.f};
  f32x4 dt = {0.f, 0.f, 0.f, 0.f};
#pragma unroll
  for (int kk = 0; kk < 4; ++kk) {
    int k0 = kk * 32 + kgrp * 8;
    s16x8 bs = pack_bf16x8(rs + k0);
    ds = __builtin_amdgcn_mfma_f32_16x16x32_bf16(afrag[kk], bs, ds, 0, 0, 0);
    s16x8 bt = pack_bf16x8(rt + k0);
    dt = __builtin_amdgcn_mfma_f32_16x16x32_bf16(afrag[kk], bt, dt, 0, 0, 0);
  }

  int ge = e0 + lcol;
  f32x4 evv;
#pragma unroll
  for (int r = 0; r < 4; ++r) {
    float tv = __shfl_xor(dt[r], 32);   // lane kgrp -> kgrp+2: dt row h+8
    float s = ds[r] + tv;
    s = s > 0.f ? s : 0.2f * s;         // leaky_relu, NEG_SLOPE=0.2
    evv[r] = __expf(s);
  }
  if (kgrp < 2 && ge < n) {
    int seg = index[ge];
#pragma unroll
    for (int r = 0; r < 4; ++r) atomicAdd(&denom[seg * 8 + kgrp * 4 + r], evv[r]);
    *(f32x4*)(ex + (size_t)ge * 8 + kgrp * 4) = evv;
  }
}

// ---------------------------------------------------------------------------
// gemm: proj_tgt^T = Wb . msg_tgt^T via MFMA; A = Wb rows (features),
// B = msg_tgt (K x edges). C: row = feature (kgrp*4+r), col = edge (lane&15)
// -> lane holds 4 CONSECUTIVE features of one edge -> float4 stores.
// Block = 64 edges x 256 features; wave w owns features [w*64, w*64+64).
// R6 experiment: REGULAR cached stores (was nontemporal) so L2 merges the
// 64 B chunks into full lines before HBM.
// ---------------------------------------------------------------------------
__global__ __launch_bounds__(256) void gemm_kernel(
    const float* __restrict__ msg, const int* __restrict__ index,
    const unsigned short* __restrict__ Wb, const float* __restrict__ ex,
    const float* __restrict__ denom, float* __restrict__ out, int n) {
  __shared__ float att_lds[64][9];
  int tid = threadIdx.x;
  int mbase = blockIdx.x * 64;

  for (int i = tid; i < 512; i += 256) {
    int r = i >> 3, h = i & 7;
    int ge = mbase + r;
    float a = 0.f;
    if (ge < n) {
      int seg = index[ge];
      a = ex[(size_t)ge * 8 + h] / (denom[seg * 8 + h] + 1e-16f);
    }
    att_lds[r][h] = a;
  }
  __syncthreads();

  int w = tid >> 6, l = tid & 63;
  int lcol = l & 15;
  int kgrp = l >> 4;

  // A-frags: wave w's 4 feature-tiles, loaded once (Wb is L2-resident)
  s16x8 afrag[4][4];
#pragma unroll
  for (int ct = 0; ct < 4; ++ct) {
    int feat = w * 64 + ct * 16 + lcol;
#pragma unroll
    for (int kk = 0; kk < 4; ++kk)
      afrag[ct][kk] = *(const s16x8*)(Wb + (size_t)feat * 128 + kk * 32 + kgrp * 8);
  }

  for (int t = 0; t < 4; ++t) {
    int e0 = mbase + t * 16;
    int grow = e0 + lcol;
    int ga = grow < n ? grow : n - 1;
    const float* brow = msg + ((size_t)ga + (size_t)n) * 128;  // msg_tgt row

    s16x8 bfrag[4];
#pragma unroll
    for (int kk = 0; kk < 4; ++kk) bfrag[kk] = pack_bf16x8(brow + kk * 32 + kgrp * 8);

    int ge = e0 + lcol;
    bool ok = ge < n;
    size_t ob = (size_t)ge * 256;
    size_t pb = ((size_t)ge + (size_t)n) * 256;

#pragma unroll
    for (int ct = 0; ct < 4; ++ct) {
      f32x4 acc = {0.f, 0.f, 0.f, 0.f};
#pragma unroll
      for (int kk = 0; kk < 4; ++kk)
        acc = __builtin_amdgcn_mfma_f32_16x16x32_bf16(afrag[ct][kk], bfrag[kk], acc, 0, 0, 0);
      int f0 = w * 64 + ct * 16 + kgrp * 4;
      if (ok) {
        float a = att_lds[t * 16 + lcol][f0 >> 5];
        f32x4 wv = acc * a;
        *(f32x4*)(out + ob + f0) = wv;     // regular store (A/B vs NT)
        *(f32x4*)(out + pb + f0) = acc;    // regular store (A/B vs NT)
      }
    }
  }
}

// ---------------------------------------------------------------------------
extern "C" void kernel_launch(void* const* d_in, const int* in_sizes, int n_in,
                              void* d_out, int out_size, void* d_ws, size_t ws_size,
                              hipStream_t stream) {
  const float* messages = (const float*)d_in[0];
  const float* W        = (const float*)d_in[1];
  const float* a_src    = (const float*)d_in[2];
  const float* a_tgt    = (const float*)d_in[3];
  const int*   index    = (const int*)d_in[4];
  int n = in_sizes[4];  // n_edges = 250000

  char* ws = (char*)d_ws;
  unsigned short* Wb     = (unsigned short*)(ws);             // 64 KB
  unsigned short* wb_cat = (unsigned short*)(ws + 65536);     // 4 KB
  float* denom           = (float*)(ws + 69632);              // 1.6 MB
  float* ex              = (float*)(ws + 69632 + 1600000);    // 8 MB
  float* out = (float*)d_out;

  int nblk = (n + 63) / 64;
  prep_kernel<<<(NSEG * 8 + 255) / 256, 256, 0, stream>>>(W, a_src, a_tgt, Wb,
                                                          wb_cat, denom);
  score_kernel<<<nblk, 256, 0, stream>>>(messages, index, wb_cat, ex, denom, n);
  gemm_kernel<<<nblk, 256, 0, stream>>>(messages, index, Wb, ex, denom, out, n);
}

// Round 7
// 189.123 us; speedup vs baseline: 1.5104x; 1.5104x over previous
//
#include <hip/hip_runtime.h>
#include <hip/hip_bf16.h>

#define NSEG 50000

typedef __attribute__((ext_vector_type(4))) float f32x4;
typedef __attribute__((ext_vector_type(8))) short s16x8;

static __device__ __forceinline__ unsigned short f2bf(float f) {
  unsigned int u = __float_as_uint(f);
  u += 0x7fffu + ((u >> 16) & 1u);   // round-to-nearest-even
  return (unsigned short)(u >> 16);
}

static __device__ __forceinline__ s16x8 pack_bf16x8(const float* p) {
  float4 p0 = *(const float4*)(p);
  float4 p1 = *(const float4*)(p + 4);
  s16x8 v;
  v[0] = (short)f2bf(p0.x); v[1] = (short)f2bf(p0.y);
  v[2] = (short)f2bf(p0.z); v[3] = (short)f2bf(p0.w);
  v[4] = (short)f2bf(p1.x); v[5] = (short)f2bf(p1.y);
  v[6] = (short)f2bf(p1.z); v[7] = (short)f2bf(p1.w);
  return v;
}

// ---------------------------------------------------------------------------
// prep: Wb = bf16(W) [256x128];  wb_cat[16][128] bf16 (rows 0-7: a_src-folded
// heads, rows 8-15: a_tgt-folded).  (denom zeroed by hipMemsetAsync.)
// ---------------------------------------------------------------------------
__global__ __launch_bounds__(256) void prep_kernel(
    const float* __restrict__ W, const float* __restrict__ a_src,
    const float* __restrict__ a_tgt, unsigned short* __restrict__ Wb,
    unsigned short* __restrict__ wb_cat) {
  int t = blockIdx.x * 256 + threadIdx.x;
  if (t < 32768) Wb[t] = f2bf(W[t]);
  if (t < 2048) {
    int row = t >> 7, k = t & 127;
    int h = row & 7;
    const float* a = (row < 8) ? a_src : a_tgt;
    float acc = 0.f;
    for (int f = 0; f < 32; ++f) acc += W[(h * 32 + f) * 128 + k] * a[h * 32 + f];
    wb_cat[t] = f2bf(acc);
  }
}

// ---------------------------------------------------------------------------
// score: MFMA, A = wb_cat (16 rows x 128 K), B = msg rows (K x 16 edges).
// C layout: row = kgrp*4+r (head), col = lane&15 (edge).
// ---------------------------------------------------------------------------
__global__ __launch_bounds__(256) void score_kernel(
    const float* __restrict__ msg, const int* __restrict__ index,
    const unsigned short* __restrict__ wb_cat, float* __restrict__ ex,
    float* __restrict__ denom, int n) {
  int tid = threadIdx.x;
  int w = tid >> 6, l = tid & 63;
  int lcol = l & 15;   // A row / B col (edge) within tile
  int kgrp = l >> 4;   // k-chunk of 8
  int e0 = blockIdx.x * 64 + w * 16;
  int grow = e0 + lcol;
  int ga = grow < n ? grow : n - 1;
  const float* rs = msg + (size_t)ga * 128;                // msg_src row
  const float* rt = msg + ((size_t)ga + (size_t)n) * 128;  // msg_tgt row

  s16x8 afrag[4];
#pragma unroll
  for (int kk = 0; kk < 4; ++kk)
    afrag[kk] = *(const s16x8*)(wb_cat + lcol * 128 + kk * 32 + kgrp * 8);

  f32x4 ds = {0.f, 0.f, 0.f, 0.f};
  f32x4 dt = {0.f, 0.f, 0.f, 0.f};
#pragma unroll
  for (int kk = 0; kk < 4; ++kk) {
    int k0 = kk * 32 + kgrp * 8;
    s16x8 bs = pack_bf16x8(rs + k0);
    ds = __builtin_amdgcn_mfma_f32_16x16x32_bf16(afrag[kk], bs, ds, 0, 0, 0);
    s16x8 bt = pack_bf16x8(rt + k0);
    dt = __builtin_amdgcn_mfma_f32_16x16x32_bf16(afrag[kk], bt, dt, 0, 0, 0);
  }

  int ge = e0 + lcol;
  f32x4 evv;
#pragma unroll
  for (int r = 0; r < 4; ++r) {
    float tv = __shfl_xor(dt[r], 32);   // lane kgrp -> kgrp+2: dt row h+8
    float s = ds[r] + tv;
    s = s > 0.f ? s : 0.2f * s;         // leaky_relu, NEG_SLOPE=0.2
    evv[r] = __expf(s);
  }
  if (kgrp < 2 && ge < n) {
    int seg = index[ge];
#pragma unroll
    for (int r = 0; r < 4; ++r) atomicAdd(&denom[seg * 8 + kgrp * 4 + r], evv[r]);
    *(f32x4*)(ex + (size_t)ge * 8 + kgrp * 4) = evv;
  }
}

// ---------------------------------------------------------------------------
// gemm: proj_tgt^T = Wb . msg_tgt^T via MFMA; A = Wb rows (features),
// B = msg_tgt (K x edges). C: row = feature (kgrp*4+r), col = edge (lane&15).
// R7: LDS-bounce epilogue — stage each 16-edge x 256-feat tile (both output
// halves) in LDS, then each wave emits 1 KB fully-contiguous NT stores
// (one edge row per instruction).
// ---------------------------------------------------------------------------
__global__ __launch_bounds__(256) void gemm_kernel(
    const float* __restrict__ msg, const int* __restrict__ index,
    const unsigned short* __restrict__ Wb, const float* __restrict__ ex,
    const float* __restrict__ denom, float* __restrict__ out, int n) {
  __shared__ float att_lds[64][9];
  __shared__ float stg[2][16][260];   // [half][edge][feat], stride 260 (%32==4)
  int tid = threadIdx.x;
  int mbase = blockIdx.x * 64;

  for (int i = tid; i < 512; i += 256) {
    int r = i >> 3, h = i & 7;
    int ge = mbase + r;
    float a = 0.f;
    if (ge < n) {
      int seg = index[ge];
      a = ex[(size_t)ge * 8 + h] / (denom[seg * 8 + h] + 1e-16f);
    }
    att_lds[r][h] = a;
  }
  __syncthreads();

  int w = tid >> 6, l = tid & 63;
  int lcol = l & 15;
  int kgrp = l >> 4;

  // A-frags: wave w's 4 feature-tiles, loaded once (Wb is L2-resident)
  s16x8 afrag[4][4];
#pragma unroll
  for (int ct = 0; ct < 4; ++ct) {
    int feat = w * 64 + ct * 16 + lcol;
#pragma unroll
    for (int kk = 0; kk < 4; ++kk)
      afrag[ct][kk] = *(const s16x8*)(Wb + (size_t)feat * 128 + kk * 32 + kgrp * 8);
  }

  for (int t = 0; t < 4; ++t) {
    int e0 = mbase + t * 16;
    int grow = e0 + lcol;
    int ga = grow < n ? grow : n - 1;
    const float* brow = msg + ((size_t)ga + (size_t)n) * 128;  // msg_tgt row

    s16x8 bfrag[4];
#pragma unroll
    for (int kk = 0; kk < 4; ++kk) bfrag[kk] = pack_bf16x8(brow + kk * 32 + kgrp * 8);

    // compute + stage into LDS
#pragma unroll
    for (int ct = 0; ct < 4; ++ct) {
      f32x4 acc = {0.f, 0.f, 0.f, 0.f};
#pragma unroll
      for (int kk = 0; kk < 4; ++kk)
        acc = __builtin_amdgcn_mfma_f32_16x16x32_bf16(afrag[ct][kk], bfrag[kk], acc, 0, 0, 0);
      int f0 = w * 64 + ct * 16 + kgrp * 4;
      float a = att_lds[t * 16 + lcol][f0 >> 5];
      *(f32x4*)&stg[0][lcol][f0] = acc * a;
      *(f32x4*)&stg[1][lcol][f0] = acc;
    }
    __syncthreads();

    // write out: wave w writes edges er = rnd*4 + w; 1 KB contiguous per store
#pragma unroll
    for (int rnd = 0; rnd < 4; ++rnd) {
      int er = rnd * 4 + w;
      int ge = mbase + t * 16 + er;
      if (ge < n) {
        f32x4 v0 = *(const f32x4*)(&stg[0][er][0] + l * 4);
        __builtin_nontemporal_store(v0, (f32x4*)(out + (size_t)ge * 256 + l * 4));
        f32x4 v1 = *(const f32x4*)(&stg[1][er][0] + l * 4);
        __builtin_nontemporal_store(v1, (f32x4*)(out + ((size_t)ge + (size_t)n) * 256 + l * 4));
      }
    }
    __syncthreads();
  }
}

// ---------------------------------------------------------------------------
extern "C" void kernel_launch(void* const* d_in, const int* in_sizes, int n_in,
                              void* d_out, int out_size, void* d_ws, size_t ws_size,
                              hipStream_t stream) {
  const float* messages = (const float*)d_in[0];
  const float* W        = (const float*)d_in[1];
  const float* a_src    = (const float*)d_in[2];
  const float* a_tgt    = (const float*)d_in[3];
  const int*   index    = (const int*)d_in[4];
  int n = in_sizes[4];  // n_edges = 250000

  char* ws = (char*)d_ws;
  unsigned short* Wb     = (unsigned short*)(ws);             // 64 KB
  unsigned short* wb_cat = (unsigned short*)(ws + 65536);     // 4 KB
  float* denom           = (float*)(ws + 69632);              // 1.6 MB
  float* ex              = (float*)(ws + 69632 + 1600000);    // 8 MB
  float* out = (float*)d_out;

  int nblk = (n + 63) / 64;
  hipMemsetAsync(denom, 0, NSEG * 8 * sizeof(float), stream);
  prep_kernel<<<128, 256, 0, stream>>>(W, a_src, a_tgt, Wb, wb_cat);
  score_kernel<<<nblk, 256, 0, stream>>>(messages, index, wb_cat, ex, denom, n);
  gemm_kernel<<<nblk, 256, 0, stream>>>(messages, index, Wb, ex, denom, out, n);
}

// Round 8
// 186.149 us; speedup vs baseline: 1.5346x; 1.0160x over previous
//
#include <hip/hip_runtime.h>
#include <hip/hip_bf16.h>

#define NSEG 50000

typedef __attribute__((ext_vector_type(4))) float f32x4;
typedef __attribute__((ext_vector_type(8))) short s16x8;

static __device__ __forceinline__ unsigned short f2bf(float f) {
  unsigned int u = __float_as_uint(f);
  u += 0x7fffu + ((u >> 16) & 1u);   // round-to-nearest-even
  return (unsigned short)(u >> 16);
}

static __device__ __forceinline__ s16x8 pack_bf16x8(const float* p) {
  float4 p0 = *(const float4*)(p);
  float4 p1 = *(const float4*)(p + 4);
  s16x8 v;
  v[0] = (short)f2bf(p0.x); v[1] = (short)f2bf(p0.y);
  v[2] = (short)f2bf(p0.z); v[3] = (short)f2bf(p0.w);
  v[4] = (short)f2bf(p1.x); v[5] = (short)f2bf(p1.y);
  v[6] = (short)f2bf(p1.z); v[7] = (short)f2bf(p1.w);
  return v;
}

// ---------------------------------------------------------------------------
// prep: Wb = bf16(W) [256x128];  wb_cat[16][128] bf16 (rows 0-7: a_src-folded
// heads, rows 8-15: a_tgt-folded);  denom = 0.  (grid 1563 blocks)
// ---------------------------------------------------------------------------
__global__ __launch_bounds__(256) void prep_kernel(
    const float* __restrict__ W, const float* __restrict__ a_src,
    const float* __restrict__ a_tgt, unsigned short* __restrict__ Wb,
    unsigned short* __restrict__ wb_cat, float* __restrict__ denom) {
  int t = blockIdx.x * 256 + threadIdx.x;
  if (t < 32768) Wb[t] = f2bf(W[t]);
  if (t < 2048) {
    int row = t >> 7, k = t & 127;
    int h = row & 7;
    const float* a = (row < 8) ? a_src : a_tgt;
    float acc = 0.f;
    for (int f = 0; f < 32; ++f) acc += W[(h * 32 + f) * 128 + k] * a[h * 32 + f];
    wb_cat[t] = f2bf(acc);
  }
  if (t < NSEG * 8) denom[t] = 0.f;
}

// ---------------------------------------------------------------------------
// score: MFMA, A = wb_cat (16 rows x 128 K), B = msg rows (K x 16 edges).
// C layout: row = kgrp*4+r (head), col = lane&15 (edge).
// ---------------------------------------------------------------------------
__global__ __launch_bounds__(256) void score_kernel(
    const float* __restrict__ msg, const int* __restrict__ index,
    const unsigned short* __restrict__ wb_cat, float* __restrict__ ex,
    float* __restrict__ denom, int n) {
  int tid = threadIdx.x;
  int w = tid >> 6, l = tid & 63;
  int lcol = l & 15;   // A row / B col (edge) within tile
  int kgrp = l >> 4;   // k-chunk of 8
  int e0 = blockIdx.x * 64 + w * 16;
  int grow = e0 + lcol;
  int ga = grow < n ? grow : n - 1;
  const float* rs = msg + (size_t)ga * 128;                // msg_src row
  const float* rt = msg + ((size_t)ga + (size_t)n) * 128;  // msg_tgt row

  s16x8 afrag[4];
#pragma unroll
  for (int kk = 0; kk < 4; ++kk)
    afrag[kk] = *(const s16x8*)(wb_cat + lcol * 128 + kk * 32 + kgrp * 8);

  f32x4 ds = {0.f, 0.f, 0.f, 0.f};
  f32x4 dt = {0.f, 0.f, 0.f, 0.f};
#pragma unroll
  for (int kk = 0; kk < 4; ++kk) {
    int k0 = kk * 32 + kgrp * 8;
    s16x8 bs = pack_bf16x8(rs + k0);
    ds = __builtin_amdgcn_mfma_f32_16x16x32_bf16(afrag[kk], bs, ds, 0, 0, 0);
    s16x8 bt = pack_bf16x8(rt + k0);
    dt = __builtin_amdgcn_mfma_f32_16x16x32_bf16(afrag[kk], bt, dt, 0, 0, 0);
  }

  int ge = e0 + lcol;
  f32x4 evv;
#pragma unroll
  for (int r = 0; r < 4; ++r) {
    float tv = __shfl_xor(dt[r], 32);   // lane kgrp -> kgrp+2: dt row h+8
    float s = ds[r] + tv;
    s = s > 0.f ? s : 0.2f * s;         // leaky_relu, NEG_SLOPE=0.2
    evv[r] = __expf(s);
  }
  if (kgrp < 2 && ge < n) {
    int seg = index[ge];
#pragma unroll
    for (int r = 0; r < 4; ++r) atomicAdd(&denom[seg * 8 + kgrp * 4 + r], evv[r]);
    *(f32x4*)(ex + (size_t)ge * 8 + kgrp * 4) = evv;
  }
}

// ---------------------------------------------------------------------------
// gemm: proj_tgt^T = Wb . msg_tgt^T via MFMA; A = Wb rows (features),
// B = msg_tgt (K x edges). C: row = feature (kgrp*4+r), col = edge (lane&15).
// LDS-bounce epilogue (1 KB contiguous NT stores per instruction).
// R8: raw s_barrier + lgkmcnt(0)-only waits in the t-loop so NT stores are
// never drained at barriers (T3/T4 pattern; __syncthreads would vmcnt(0)).
// ---------------------------------------------------------------------------
__global__ __launch_bounds__(256) void gemm_kernel(
    const float* __restrict__ msg, const int* __restrict__ index,
    const unsigned short* __restrict__ Wb, const float* __restrict__ ex,
    const float* __restrict__ denom, float* __restrict__ out, int n) {
  __shared__ float att_lds[64][9];
  __shared__ float stg[2][16][260];   // [half][edge][feat], stride 260 (%32==4)
  int tid = threadIdx.x;
  int mbase = blockIdx.x * 64;

  for (int i = tid; i < 512; i += 256) {
    int r = i >> 3, h = i & 7;
    int ge = mbase + r;
    float a = 0.f;
    if (ge < n) {
      int seg = index[ge];
      a = ex[(size_t)ge * 8 + h] / (denom[seg * 8 + h] + 1e-16f);
    }
    att_lds[r][h] = a;
  }
  __syncthreads();

  int w = tid >> 6, l = tid & 63;
  int lcol = l & 15;
  int kgrp = l >> 4;

  // A-frags: wave w's 4 feature-tiles, loaded once (Wb is L2-resident)
  s16x8 afrag[4][4];
#pragma unroll
  for (int ct = 0; ct < 4; ++ct) {
    int feat = w * 64 + ct * 16 + lcol;
#pragma unroll
    for (int kk = 0; kk < 4; ++kk)
      afrag[ct][kk] = *(const s16x8*)(Wb + (size_t)feat * 128 + kk * 32 + kgrp * 8);
  }

  for (int t = 0; t < 4; ++t) {
    int e0 = mbase + t * 16;
    int grow = e0 + lcol;
    int ga = grow < n ? grow : n - 1;
    const float* brow = msg + ((size_t)ga + (size_t)n) * 128;  // msg_tgt row

    s16x8 bfrag[4];
#pragma unroll
    for (int kk = 0; kk < 4; ++kk) bfrag[kk] = pack_bf16x8(brow + kk * 32 + kgrp * 8);

    // compute + stage into LDS
#pragma unroll
    for (int ct = 0; ct < 4; ++ct) {
      f32x4 acc = {0.f, 0.f, 0.f, 0.f};
#pragma unroll
      for (int kk = 0; kk < 4; ++kk)
        acc = __builtin_amdgcn_mfma_f32_16x16x32_bf16(afrag[ct][kk], bfrag[kk], acc, 0, 0, 0);
      int f0 = w * 64 + ct * 16 + kgrp * 4;
      float a = att_lds[t * 16 + lcol][f0 >> 5];
      *(f32x4*)&stg[0][lcol][f0] = acc * a;
      *(f32x4*)&stg[1][lcol][f0] = acc;
    }
    asm volatile("s_waitcnt lgkmcnt(0)" ::: "memory");  // LDS writes visible
    __builtin_amdgcn_s_barrier();                       // no vmcnt drain

    // write out: wave w writes edges er = rnd*4 + w; 1 KB contiguous per store
#pragma unroll
    for (int rnd = 0; rnd < 4; ++rnd) {
      int er = rnd * 4 + w;
      int ge = mbase + t * 16 + er;
      if (ge < n) {
        f32x4 v0 = *(const f32x4*)(&stg[0][er][0] + l * 4);
        __builtin_nontemporal_store(v0, (f32x4*)(out + (size_t)ge * 256 + l * 4));
        f32x4 v1 = *(const f32x4*)(&stg[1][er][0] + l * 4);
        __builtin_nontemporal_store(v1, (f32x4*)(out + ((size_t)ge + (size_t)n) * 256 + l * 4));
      }
    }
    asm volatile("s_waitcnt lgkmcnt(0)" ::: "memory");  // LDS reads done
    __builtin_amdgcn_s_barrier();                       // stores stay in flight
  }
}

// ---------------------------------------------------------------------------
extern "C" void kernel_launch(void* const* d_in, const int* in_sizes, int n_in,
                              void* d_out, int out_size, void* d_ws, size_t ws_size,
                              hipStream_t stream) {
  const float* messages = (const float*)d_in[0];
  const float* W        = (const float*)d_in[1];
  const float* a_src    = (const float*)d_in[2];
  const float* a_tgt    = (const float*)d_in[3];
  const int*   index    = (const int*)d_in[4];
  int n = in_sizes[4];  // n_edges = 250000

  char* ws = (char*)d_ws;
  unsigned short* Wb     = (unsigned short*)(ws);             // 64 KB
  unsigned short* wb_cat = (unsigned short*)(ws + 65536);     // 4 KB
  float* denom           = (float*)(ws + 69632);              // 1.6 MB
  float* ex              = (float*)(ws + 69632 + 1600000);    // 8 MB
  float* out = (float*)d_out;

  int nblk = (n + 63) / 64;
  prep_kernel<<<(NSEG * 8 + 255) / 256, 256, 0, stream>>>(W, a_src, a_tgt, Wb,
                                                          wb_cat, denom);
  score_kernel<<<nblk, 256, 0, stream>>>(messages, index, wb_cat, ex, denom, n);
  gemm_kernel<<<nblk, 256, 0, stream>>>(messages, index, Wb, ex, denom, out, n);
}